// Round 13
// baseline (547.758 us; speedup 1.0000x reference)
//
#include <hip/hip_runtime.h>
#include <math.h>

// ---------------------------------------------------------------------------
// densityPropGRUCell: B=16, IN=U=1024.
// Round 13: GEMM core reverted to the round-6 quadrant pipeline (4-buffer
// BK=32 ring, ONE barrier + counted vmcnt(4) per K-step — fastest measured at
// the 2-waves/SIMD occupancy this 244-reg kernel allows). All round-12
// epilogue fusions kept (OMODE 1 Sigma_z, OMODE 3 sigma_g, OMODE 2 combine).
// ---------------------------------------------------------------------------

#define B_  16
#define N_  1024
#define NN_ (1024*1024)

typedef __bf16 bf16x8 __attribute__((ext_vector_type(8)));
typedef float  f32x4  __attribute__((ext_vector_type(4)));
typedef unsigned short ushort8v __attribute__((ext_vector_type(8)));

__device__ __forceinline__ unsigned short f2bf(float f) {
  union { float f; unsigned int u; } v; v.f = f;
  unsigned int r = v.u + 0x7fffu + ((v.u >> 16) & 1u);   // RNE
  return (unsigned short)(r >> 16);
}
__device__ __forceinline__ float bf2f(unsigned short h) {
  union { unsigned int u; float f; } v; v.u = ((unsigned int)h) << 16;
  return v.f;
}

__device__ __forceinline__ void gload_lds16(const void* g, void* l) {
  __builtin_amdgcn_global_load_lds((__attribute__((address_space(1))) void*)g,
                                   (__attribute__((address_space(3))) void*)l,
                                   16, 0, 0);
}

#define MFMA_ __builtin_amdgcn_mfma_f32_16x16x32_bf16

// ---------------------------------------------------------------------------
// D[m][n] = sum_k A[m][kofx+k] * B[n][k];  M=N=1024 per (batch, pair-slice).
// 256x256 tile, BK=32, 8 waves (2M x 4N, wave tile 128x64), LDS 4 x 32KB ring,
// depth-2 prefetch, 1 barrier + vmcnt(4) per K-step, quadrant read rotation:
//  Q0(a0,b0)+rd b1 | Q1(a0,b1)+rd a1 | STAGE(kt+2);vmcnt;bar |
//  Q2(a1,b0)+rd a0'(buf kt+1) | Q3(a1,b1)+rd b0'(buf kt+1)
// OMODE 0: raw bf16 rows at col nofx; 1: scaled bf16 (Sigma_z);
// OMODE 3: r-gate fused sigma_g -> bf16 (SzP=SstH, zV=r, prevV=prev);
// OMODE 2: h-gate fused combine -> f32 (SzP=Sz, SstP=Sst, zV/prevV/hV).
// PAIR=1: panel index carries ps selecting {Bm,+0} / {Bm2,+1024 kofx,nofx}.
// ---------------------------------------------------------------------------
template<int OMODE, int PAIR>
__global__ __launch_bounds__(512)
void gemmq(const unsigned short* __restrict__ A, int lda, long aStride, int koffA,
           const unsigned short* __restrict__ Bm, const unsigned short* __restrict__ Bm2,
           int ldb, long bStride, int K,
           void* __restrict__ Out, int ldo, long oStride, int noff,
           const float* __restrict__ act,
           const float* __restrict__ spU, const float* __restrict__ spW,
           const float* __restrict__ dU, const float* __restrict__ dW,
           const unsigned short* __restrict__ SzP, const float* __restrict__ SstP,
           const float* __restrict__ zV, const float* __restrict__ prevV,
           const float* __restrict__ hV)
{
  __shared__ __align__(16) char ldsb[131072];   // 4 x 32KB ring
  const int id = blockIdx.x;
  const int xcd = id & 7, rest = id >> 3;
  const int mt = rest & 3, pp = rest >> 2;
  const int panel = xcd + (pp << 3);            // (nt, b, ps)
  const int nt = panel & 3;
  const int b  = (panel >> 2) & 15;
  const int ps = PAIR ? (panel >> 6) : 0;
  const unsigned short* Bsel = (PAIR && ps) ? Bm2 : Bm;
  const int kofx = koffA + (ps ? 1024 : 0);
  const int nofx = noff  + (ps ? 1024 : 0);
  const int mbase = mt << 8, nbase = nt << 8;
  const int tid = threadIdx.x, lane = tid & 63, w = tid >> 6;
  const int wm = w >> 2, wn = w & 3;            // 2M x 4N waves
  const int NT = K >> 5;                        // K-steps of 32

  f32x4 acc[8][4];
  const f32x4 zero4 = {0.f, 0.f, 0.f, 0.f};
#pragma unroll
  for (int i = 0; i < 8; i++)
#pragma unroll
    for (int j = 0; j < 4; j++) acc[i][j] = zero4;

  // ---- staging source addressing (pre-swizzled global, linear LDS dest) ----
  const int l3 = lane >> 3, l7 = lane & 7;
  const int posg = l7 ^ l3;
  const int gr = ((w * 8 + l3) << 1) + (posg >> 2);  // row 0..127 within a half
  const int gc = (posg & 3) << 3;                    // elem col within BK=32
  const unsigned short* Ag = A + (size_t)b * aStride + (size_t)(mbase + gr) * lda + kofx + gc;
  const unsigned short* Bg = Bsel + (size_t)b * bStride + (size_t)(nbase + gr) * ldb + gc;
  const size_t a128 = (size_t)128 * lda, bb128 = (size_t)128 * ldb;
  const int wdst = w << 10;                 // wave-uniform dest offset (w*1KB)

  // ---- ds_read per-lane offset within a 1KB (16-row) frag block ----
  const int lrow = lane & 15, c4 = lane >> 4;
  const int aoff = ((lrow >> 1) << 7) + (((((lrow & 1) << 2) | c4) ^ (lrow >> 1)) << 4);
  const int abase0 = (wm << 13);            // wm*8192 within A region
  const int bbase0 = 16384 + (wn << 12);    // B region + wn*4096

  auto STAGE = [&](int kt) {
    const int p = kt & 3;
    const size_t ko = (size_t)kt << 5;
    char* base = ldsb + (p << 15);
    gload_lds16(Ag + ko,          base + wdst);
    gload_lds16(Ag + ko + a128,   base + 8192  + wdst);
    gload_lds16(Bg + ko,          base + 16384 + wdst);
    gload_lds16(Bg + ko + bb128,  base + 24576 + wdst);
  };
  auto LDA8 = [&](const char* pbuf, int mi) -> bf16x8 {
    return *(const bf16x8*)(pbuf + abase0 + (mi << 10) + aoff);
  };
  auto LDB8 = [&](const char* pbuf, int ni) -> bf16x8 {
    return *(const bf16x8*)(pbuf + bbase0 + (ni << 10) + aoff);
  };

  STAGE(0); STAGE(1);
  asm volatile("s_waitcnt vmcnt(4)" ::: "memory");
  __builtin_amdgcn_sched_barrier(0);
  __builtin_amdgcn_s_barrier();
  __builtin_amdgcn_sched_barrier(0);

  bf16x8 a0[4], a1[4], b0[2], b1[2];
#pragma unroll
  for (int i = 0; i < 4; i++) a0[i] = LDA8(ldsb, i);
#pragma unroll
  for (int i = 0; i < 2; i++) b0[i] = LDB8(ldsb, i);

  for (int kt = 0; kt < NT; ++kt) {
    const char* pbuf = ldsb + ((size_t)(kt & 3) << 15);
    const char* pnxt = ldsb + ((size_t)((kt + 1) & 3) << 15);
    // Q0: (a0,b0) -> acc[0:4][0:2], prefetch b1
#pragma unroll
    for (int i = 0; i < 2; i++) b1[i] = LDB8(pbuf, 2 + i);
#pragma unroll
    for (int ni = 0; ni < 2; ni++)
#pragma unroll
      for (int mi = 0; mi < 4; mi++)
        acc[mi][ni] = MFMA_(a0[mi], b0[ni], acc[mi][ni], 0, 0, 0);
    // Q1: (a0,b1) -> acc[0:4][2:4], prefetch a1
#pragma unroll
    for (int i = 0; i < 4; i++) a1[i] = LDA8(pbuf, 4 + i);
#pragma unroll
    for (int ni = 0; ni < 2; ni++)
#pragma unroll
      for (int mi = 0; mi < 4; mi++)
        acc[mi][2 + ni] = MFMA_(a0[mi], b1[ni], acc[mi][2 + ni], 0, 0, 0);
    // boundary: stage kt+2, counted wait for buf kt+1, barrier
    if (kt + 2 < NT) {
      STAGE(kt + 2);
      asm volatile("s_waitcnt vmcnt(4)" ::: "memory");
    } else {
      asm volatile("s_waitcnt vmcnt(0)" ::: "memory");
    }
    __builtin_amdgcn_sched_barrier(0);
    __builtin_amdgcn_s_barrier();
    __builtin_amdgcn_sched_barrier(0);
    // Q2: (a1,b0) -> acc[4:8][0:2], prefetch next a0 from buf kt+1
    if (kt + 1 < NT) {
#pragma unroll
      for (int i = 0; i < 4; i++) a0[i] = LDA8(pnxt, i);
    }
#pragma unroll
    for (int ni = 0; ni < 2; ni++)
#pragma unroll
      for (int mi = 0; mi < 4; mi++)
        acc[4 + mi][ni] = MFMA_(a1[mi], b0[ni], acc[4 + mi][ni], 0, 0, 0);
    // Q3: (a1,b1) -> acc[4:8][2:4], prefetch next b0
    if (kt + 1 < NT) {
#pragma unroll
      for (int i = 0; i < 2; i++) b0[i] = LDB8(pnxt, i);
    }
#pragma unroll
    for (int ni = 0; ni < 2; ni++)
#pragma unroll
      for (int mi = 0; mi < 4; mi++)
        acc[4 + mi][2 + ni] = MFMA_(a1[mi], b1[ni], acc[4 + mi][2 + ni], 0, 0, 0);
  }

  // ======================== epilogues ========================
  __syncthreads();                           // ring dead; reuse as scratch
  unsigned short* scr = (unsigned short*)(ldsb + w * 16384);  // 16KB/wave
  const float* actb = act ? (act + b * N_) : nullptr;
  float dUb = 0.f, dWb = 0.f;
  if (OMODE != 0) { dUb = dU[b]; dWb = dW[b]; }

  // ---- pass 1: write (scaled) tile to wave-private scratch, bf16 ----
#pragma unroll
  for (int mi = 0; mi < 8; mi++) {
    const int rl0 = mi * 16 + ((lane >> 4) << 2);
#pragma unroll
    for (int ni = 0; ni < 4; ni++) {
      const int cl = ni * 16 + (lane & 15);
#pragma unroll
      for (int r = 0; r < 4; r++) {
        const int rl = rl0 + r;
        float val = acc[mi][ni][r];
        if (OMODE != 0) {
          const int u = mbase + wm * 128 + rl, v = nbase + wn * 64 + cl;
          if (u == v) val += dUb * spU[u] + dWb * spW[u];
          val *= actb[u] * actb[v];
        }
        scr[rl * 64 + ((((cl >> 3) ^ (rl & 7))) << 3) + (cl & 7)] = f2bf(val);
      }
    }
  }
  asm volatile("s_waitcnt lgkmcnt(0)" ::: "memory");
  __builtin_amdgcn_sched_barrier(0);

  // ---- pass 2: read back 8-wide, finish, store coalesced ----
#pragma unroll
  for (int pq = 0; pq < 16; pq++) {
    const int row = pq * 8 + (lane >> 3);
    const int slot = lane & 7;
    const int ch = slot ^ (row & 7);              // chunk held in this slot
    const int u = mbase + wm * 128 + row;
    const int v0 = nbase + wn * 64 + (ch << 3);
    ushort8v s8 = *(const ushort8v*)&scr[row * 64 + (slot << 3)];
    if (OMODE == 0 || OMODE == 1) {
      unsigned short* ob = (unsigned short*)Out + (size_t)b * oStride
                         + (size_t)u * ldo + nofx + v0;
      *(ushort8v*)ob = s8;
    } else if (OMODE == 3) {
      // sigma_g = stt*srv + p_u p_v srv + r_u r_v stt   (SzP=SstH, zV=r)
      const float pu = prevV[b * N_ + u];
      const float ru = zV[b * N_ + u];
      const ushort8v st8 = *(const ushort8v*)(SzP + (size_t)b * NN_ + (size_t)u * N_ + v0);
      const f32x4 pv0 = *(const f32x4*)(prevV + b * N_ + v0);
      const f32x4 pv1 = *(const f32x4*)(prevV + b * N_ + v0 + 4);
      const f32x4 rv0 = *(const f32x4*)(zV + b * N_ + v0);
      const f32x4 rv1 = *(const f32x4*)(zV + b * N_ + v0 + 4);
      ushort8v o8;
#pragma unroll
      for (int q = 0; q < 8; q++) {
        const float srv = bf2f((unsigned short)s8[q]);
        const float stt = bf2f((unsigned short)st8[q]);
        const float pv = (q < 4) ? pv0[q] : pv1[q - 4];
        const float rv = (q < 4) ? rv0[q] : rv1[q - 4];
        o8[q] = f2bf(stt * srv + pu * pv * srv + ru * rv * stt);
      }
      unsigned short* ob = (unsigned short*)Out + (size_t)b * oStride
                         + (size_t)u * ldo + v0;
      *(ushort8v*)ob = o8;
    } else {  // OMODE 2: full Sigma_out combine
      const float zu = zV[b * N_ + u];
      const float pu = prevV[b * N_ + u];
      const float hu = hV[b * N_ + u];
      const ushort8v sz8 = *(const ushort8v*)(SzP + (size_t)b * NN_ + (size_t)u * N_ + v0);
      const f32x4 st0 = *(const f32x4*)(SstP + (size_t)b * NN_ + (size_t)u * N_ + v0);
      const f32x4 st1 = *(const f32x4*)(SstP + (size_t)b * NN_ + (size_t)u * N_ + v0 + 4);
      const f32x4 zv0 = *(const f32x4*)(zV + b * N_ + v0);
      const f32x4 zv1 = *(const f32x4*)(zV + b * N_ + v0 + 4);
      const f32x4 pv0 = *(const f32x4*)(prevV + b * N_ + v0);
      const f32x4 pv1 = *(const f32x4*)(prevV + b * N_ + v0 + 4);
      const f32x4 hv0 = *(const f32x4*)(hV + b * N_ + v0);
      const f32x4 hv1 = *(const f32x4*)(hV + b * N_ + v0 + 4);
      f32x4 o0, o1;
#pragma unroll
      for (int q = 0; q < 8; q++) {
        const float shh = bf2f((unsigned short)s8[q]);
        const float szv = bf2f((unsigned short)sz8[q]);
        const float stt = (q < 4) ? st0[q] : st1[q - 4];
        const float zv  = (q < 4) ? zv0[q] : zv1[q - 4];
        const float pv  = (q < 4) ? pv0[q] : pv1[q - 4];
        const float hv  = (q < 4) ? hv0[q] : hv1[q - 4];
        float res = szv * stt + zu * zv * stt + pu * pv * szv
                  + szv * shh + (1.f - zu) * (1.f - zv) * shh + hu * hv * szv
                  - szv * (pu * hv) - szv * (hu * pv);
        if (!isfinite(res)) res = 0.f;
        if (u == v0 + q) res = fabsf(res);
        if (q < 4) o0[q] = res; else o1[q - 4] = res;
      }
      float* ob = (float*)Out + (size_t)b * oStride + (size_t)u * ldo + v0;
      *(f32x4*)ob = o0;
      *(f32x4*)(ob + 4) = o1;
    }
  }
}

// --------------------------- small kernels ---------------------------------

// both conversions in one launch: y-dim selects tensor
__global__ void conv_bf16_2(const float* __restrict__ in0, unsigned short* __restrict__ out0,
                            const float* __restrict__ in1, unsigned short* __restrict__ out1,
                            int n4)
{
  const float* in = blockIdx.y ? in1 : in0;
  unsigned short* out = blockIdx.y ? out1 : out0;
  int i = blockIdx.x * 256 + threadIdx.x;
  const int stride = gridDim.x * 256;
  for (; i < n4; i += stride) {
    const float4 v = ((const float4*)in)[i];
    ushort4 o;
    o.x = f2bf(v.x); o.y = f2bf(v.y); o.z = f2bf(v.z); o.w = f2bf(v.w);
    ((ushort4*)out)[i] = o;
  }
}

// AT_g[u][k] = (k<1024 ? U_g[k][u] : W_g[k-1024][u]) as bf16. grid(32,64,3).
__global__ void build_AT(const float* __restrict__ Uz, const float* __restrict__ Wz,
                         const float* __restrict__ Ur, const float* __restrict__ Wr,
                         const float* __restrict__ Uh, const float* __restrict__ Wh,
                         unsigned short* __restrict__ AT)
{
  __shared__ float tile[32][33];
  const int g = blockIdx.z;
  const float* U = g == 0 ? Uz : (g == 1 ? Ur : Uh);
  const float* W = g == 0 ? Wz : (g == 1 ? Wr : Wh);
  const int u0  = blockIdx.x * 32;
  const int k0g = blockIdx.y * 32;
  const float* src = (k0g >= 1024) ? W : U;
  const int kloc = k0g & 1023;
  const int tx = threadIdx.x & 31, ty = threadIdx.x >> 5;
  unsigned short* out = AT + (size_t)g * N_ * 2048;
#pragma unroll
  for (int i = 0; i < 32; i += 8) tile[ty + i][tx] = src[(size_t)(kloc + ty + i) * N_ + u0 + tx];
  __syncthreads();
#pragma unroll
  for (int i = 0; i < 32; i += 8)
    out[(size_t)(u0 + ty + i) * 2048 + k0g + tx] = f2bf(tile[tx][ty + i]);
}

__global__ void softplus6(const float* a0, const float* a1, const float* a2,
                          const float* a3, const float* a4, const float* a5,
                          float* __restrict__ sp)
{
  const float* src[6] = {a0, a1, a2, a3, a4, a5};
  const int g = blockIdx.x;
  const float* s = src[g];
  for (int i = threadIdx.x; i < N_; i += 256) {
    float x = s[i];
    sp[g * N_ + i] = (x > 20.f) ? x : log1pf(expf(x));
  }
}

__global__ void scalars1(const float* __restrict__ mu, const float* __restrict__ prev,
                         const float* __restrict__ sin_, const float* __restrict__ Sst,
                         float* __restrict__ dA, float* __restrict__ dBzr)
{
  __shared__ float red[256];
  const int b = blockIdx.x;
  float s1 = 0.f, s2 = 0.f;
  for (int i = threadIdx.x; i < N_; i += 256) {
    const float m = mu[b * N_ + i];
    s1 += m * m + sin_[(size_t)b * NN_ + (size_t)i * (N_ + 1)];
    const float p = prev[b * N_ + i];
    s2 += p * p + Sst[(size_t)b * NN_ + (size_t)i * (N_ + 1)];
  }
  red[threadIdx.x] = s1; __syncthreads();
  for (int s = 128; s > 0; s >>= 1) { if (threadIdx.x < s) red[threadIdx.x] += red[threadIdx.x + s]; __syncthreads(); }
  if (threadIdx.x == 0) dA[b] = red[0];
  __syncthreads();
  red[threadIdx.x] = s2; __syncthreads();
  for (int s = 128; s > 0; s >>= 1) { if (threadIdx.x < s) red[threadIdx.x] += red[threadIdx.x + s]; __syncthreads(); }
  if (threadIdx.x == 0) dBzr[b] = red[0];
}

// ---- gate pre-activations, split-K partials (deterministic, no atomics) ----
__global__ __launch_bounds__(256)
void gate_pre2(const float* __restrict__ x1, const float* __restrict__ x2,
               const float* __restrict__ U0, const float* __restrict__ W0,
               const float* __restrict__ U1, const float* __restrict__ W1,
               float* __restrict__ Ppart)
{
  const int g  = blockIdx.z;
  const int ks = blockIdx.y;
  const int out = blockIdx.x * 256 + threadIdx.x;
  const int b = out >> 10, col = out & 1023;
  const float* x = (ks < 4) ? x1 : x2;
  const float* Wm = (g == 0) ? ((ks < 4) ? U0 : W0) : ((ks < 4) ? U1 : W1);
  const int k0 = (ks & 3) * 256;
  const float* xb = x + b * N_ + k0;
  const float* wp = Wm + (size_t)k0 * N_ + col;
  float acc = 0.f;
#pragma unroll 8
  for (int k = 0; k < 256; k++)
    acc += xb[k] * wp[(size_t)k * N_];
  Ppart[(g * 8 + ks) * (B_ * N_) + out] = acc;
}

__global__ void gate_act2(const float* __restrict__ P,
                          float* __restrict__ z, float* __restrict__ gz,
                          float* __restrict__ r, float* __restrict__ gr)
{
  const int out = blockIdx.x * 256 + threadIdx.x;
  float a0 = 0.f, a1 = 0.f;
#pragma unroll
  for (int ks = 0; ks < 8; ks++) {
    a0 += P[ks * (B_ * N_) + out];
    a1 += P[(8 + ks) * (B_ * N_) + out];
  }
  const float s0 = 1.f / (1.f + expf(-a0));
  const float s1 = 1.f / (1.f + expf(-a1));
  z[out] = s0; gz[out] = s0 * (1.f - s0);
  r[out] = s1; gr[out] = s1 * (1.f - s1);
}

__global__ __launch_bounds__(256)
void gate_pre1(const float* __restrict__ x1, const float* __restrict__ x2,
               const float* __restrict__ U0, const float* __restrict__ W0,
               float* __restrict__ Ppart)
{
  const int ks = blockIdx.y;
  const int out = blockIdx.x * 256 + threadIdx.x;
  const int b = out >> 10, col = out & 1023;
  const float* x = (ks < 4) ? x1 : x2;
  const float* Wm = (ks < 4) ? U0 : W0;
  const int k0 = (ks & 3) * 256;
  const float* xb = x + b * N_ + k0;
  const float* wp = Wm + (size_t)k0 * N_ + col;
  float acc = 0.f;
#pragma unroll 8
  for (int k = 0; k < 256; k++)
    acc += xb[k] * wp[(size_t)k * N_];
  Ppart[ks * (B_ * N_) + out] = acc;
}

// h, gh, and mu_out = z*prev + (1-z)*h   (mu folded in)
__global__ void gate_act1(const float* __restrict__ P,
                          const float* __restrict__ z, const float* __restrict__ prev,
                          float* __restrict__ h, float* __restrict__ gh,
                          float* __restrict__ mu_out)
{
  const int out = blockIdx.x * 256 + threadIdx.x;
  float a0 = 0.f;
#pragma unroll
  for (int ks = 0; ks < 8; ks++) a0 += P[ks * (B_ * N_) + out];
  const float s = tanhf(a0);
  h[out] = s; gh[out] = 1.f - s * s;
  const float zz = z[out];
  mu_out[out] = zz * prev[out] + (1.f - zz) * s;
}

__global__ void sr_csr(const float* __restrict__ prev, const float* __restrict__ r,
                       float* __restrict__ sr, float* __restrict__ csr)
{
  __shared__ float red[256];
  const int b = blockIdx.x;
  float s = 0.f;
  for (int i = threadIdx.x; i < N_; i += 256) {
    const float v = prev[b * N_ + i] * r[b * N_ + i];
    sr[b * N_ + i] = v;
    s += v * v;
  }
  red[threadIdx.x] = s; __syncthreads();
  for (int k = 128; k > 0; k >>= 1) { if (threadIdx.x < k) red[threadIdx.x] += red[threadIdx.x + k]; __syncthreads(); }
  if (threadIdx.x == 0) csr[b] = red[0];
}

__global__ void scalars2(const unsigned short* __restrict__ Sg,
                         const float* __restrict__ csr, float* __restrict__ dBh)
{
  __shared__ float red[256];
  const int b = blockIdx.x;
  float s = 0.f;
  for (int i = threadIdx.x; i < N_; i += 256)
    s += bf2f(Sg[(size_t)b * NN_ + (size_t)i * (N_ + 1)]);
  red[threadIdx.x] = s; __syncthreads();
  for (int k = 128; k > 0; k >>= 1) { if (threadIdx.x < k) red[threadIdx.x] += red[threadIdx.x + k]; __syncthreads(); }
  if (threadIdx.x == 0) dBh[b] = red[0] + csr[b];
}

// ---------------------------------------------------------------------------

extern "C" void kernel_launch(void* const* d_in, const int* in_sizes, int n_in,
                              void* d_out, int out_size, void* d_ws, size_t ws_size,
                              hipStream_t stream)
{
  const float* mu   = (const float*)d_in[0];
  const float* sin_ = (const float*)d_in[1];
  const float* prev = (const float*)d_in[2];
  const float* Sst  = (const float*)d_in[3];
  const float* Uz = (const float*)d_in[4];  const float* uzs = (const float*)d_in[5];
  const float* Wz = (const float*)d_in[6];  const float* wzs = (const float*)d_in[7];
  const float* Ur = (const float*)d_in[8];  const float* urs = (const float*)d_in[9];
  const float* Wr = (const float*)d_in[10]; const float* wrs = (const float*)d_in[11];
  const float* Uh = (const float*)d_in[12]; const float* uhs = (const float*)d_in[13];
  const float* Wh = (const float*)d_in[14]; const float* whs = (const float*)d_in[15];

  char* ws = (char*)d_ws;
  size_t off = 0;
  auto take = [&](size_t bytes) -> char* {
    char* p = ws + off;
    off = (off + bytes + 255) & ~(size_t)255;
    return p;
  };
  unsigned short* Tcm = (unsigned short*)take((size_t)B_ * 2048 * 1024 * 2); // 64 MB
  unsigned short* Sz  = (unsigned short*)take((size_t)B_ * NN_ * 2);        // 32 MB
  unsigned short* Sg  = (unsigned short*)take((size_t)B_ * NN_ * 2);        // 32 MB
  unsigned short* AT  = (unsigned short*)take((size_t)3 * N_ * 2048 * 2);   // 12 MB
  float* Ppart = (float*)take((size_t)16 * B_ * N_ * 4);                    // 1 MB
  float* sp   = (float*)take(6 * N_ * 4);
  float* z    = (float*)take(B_ * N_ * 4);
  float* gz   = (float*)take(B_ * N_ * 4);
  float* rr   = (float*)take(B_ * N_ * 4);
  float* gr   = (float*)take(B_ * N_ * 4);
  float* h    = (float*)take(B_ * N_ * 4);
  float* gh   = (float*)take(B_ * N_ * 4);
  float* sr   = (float*)take(B_ * N_ * 4);
  float* dA   = (float*)take(64);
  float* dBzr = (float*)take(64);
  float* dBh  = (float*)take(64);
  float* csr  = (float*)take(64);
  if (off > ws_size) return;  // workspace too small (needs ~142 MB)

  float* mu_out = (float*)d_out;
  float* SigOut = (float*)d_out + (size_t)B_ * N_;
  // bf16 copies of the two big f32 inputs live in SigOut's dead region
  // (fully overwritten by the fused h-gate stage-2 at the end).
  unsigned short* SinH = (unsigned short*)SigOut;                 // 32 MB
  unsigned short* SstH = (unsigned short*)SigOut + (size_t)B_ * NN_; // 32 MB

  const unsigned short* ATz = AT;
  const unsigned short* ATr = AT + (size_t)N_ * 2048;
  const unsigned short* ATh = AT + (size_t)2 * N_ * 2048;

  // ---- prep ----
  conv_bf16_2<<<dim3(2048, 2), 256, 0, stream>>>(sin_, SinH, Sst, SstH, B_ * NN_ / 4);
  softplus6<<<6, 256, 0, stream>>>(uzs, wzs, urs, wrs, uhs, whs, sp);
  scalars1<<<16, 256, 0, stream>>>(mu, prev, sin_, Sst, dA, dBzr);
  build_AT<<<dim3(32, 64, 3), 256, 0, stream>>>(Uz, Wz, Ur, Wr, Uh, Wh, AT);
  gate_pre2<<<dim3(64, 8, 2), 256, 0, stream>>>(mu, prev, Uz, Wz, Ur, Wr, Ppart);
  gate_act2<<<64, 256, 0, stream>>>(Ppart, z, gz, rr, gr);
  sr_csr<<<16, 256, 0, stream>>>(prev, rr, sr, csr);
  gate_pre1<<<dim3(64, 8), 256, 0, stream>>>(mu, sr, Uh, Wh, Ppart);
  gate_act1<<<64, 256, 0, stream>>>(Ppart, z, prev, h, gh, mu_out);

  const long tS = (long)2048 * 1024;

  // ---- z gate ----
  gemmq<0, 1><<<512, 512, 0, stream>>>(ATz, 2048, 0, 0, SinH, SstH, 1024, (long)NN_, 1024,
                                       Tcm, 2048, tS, 0, nullptr, nullptr, nullptr, nullptr, nullptr,
                                       nullptr, nullptr, nullptr, nullptr, nullptr);
  gemmq<1, 0><<<256, 512, 0, stream>>>(ATz, 2048, 0, 0, Tcm, nullptr, 2048, tS, 2048,
                                       Sz, 1024, (long)NN_, 0, gz, sp + 0, sp + 1024, dA, dBzr,
                                       nullptr, nullptr, nullptr, nullptr, nullptr);
  // ---- r gate (stage-2 fused with sigma_g) ----
  gemmq<0, 1><<<512, 512, 0, stream>>>(ATr, 2048, 0, 0, SinH, SstH, 1024, (long)NN_, 1024,
                                       Tcm, 2048, tS, 0, nullptr, nullptr, nullptr, nullptr, nullptr,
                                       nullptr, nullptr, nullptr, nullptr, nullptr);
  gemmq<3, 0><<<256, 512, 0, stream>>>(ATr, 2048, 0, 0, Tcm, nullptr, 2048, tS, 2048,
                                       Sg, 1024, (long)NN_, 0, gr, sp + 2048, sp + 3072, dA, dBzr,
                                       SstH, nullptr, rr, prev, nullptr);
  scalars2<<<16, 256, 0, stream>>>(Sg, csr, dBh);
  // ---- h gate (stage-2 fused with combine) ----
  gemmq<0, 1><<<512, 512, 0, stream>>>(ATh, 2048, 0, 0, SinH, Sg, 1024, (long)NN_, 1024,
                                       Tcm, 2048, tS, 0, nullptr, nullptr, nullptr, nullptr, nullptr,
                                       nullptr, nullptr, nullptr, nullptr, nullptr);
  gemmq<2, 0><<<256, 512, 0, stream>>>(ATh, 2048, 0, 0, Tcm, nullptr, 2048, tS, 2048,
                                       SigOut, 1024, (long)NN_, 0, gh, sp + 4096, sp + 5120, dA, dBh,
                                       Sz, Sst, z, prev, h);
}

// Round 14
// 513.444 us; speedup vs baseline: 1.0668x; 1.0668x over previous
//
#include <hip/hip_runtime.h>
#include <math.h>

// ---------------------------------------------------------------------------
// densityPropGRUCell: B=16, IN=U=1024.
// Round 14: r12 base (best measured, 539 µs) with the GEMM loop's redundant
// barriers stripped: 8 -> 2 barriers per K-tile. Hazard-verified sync points:
//   BAR1 (after P2 + lgkm0): all waves' B(t) reads drained before any wave's
//        B(t+2) stage overwrites that buffer region at P4.
//   BAR2 (P4, after vmcnt(4)+lgkm0): all waves' A(t)-reads drained and all
//        waves' A(t+1)/B(t+1) gloads landed before next-tile reads.
// Read-ahead register pipeline (avA/avB,bvA/bvB) retained from r10/r12.
// Epilogue fusions retained (OMODE 1 Sigma_z, 3 sigma_g, 2 combine).
// ---------------------------------------------------------------------------

#define B_  16
#define N_  1024
#define NN_ (1024*1024)

typedef __bf16 bf16x8 __attribute__((ext_vector_type(8)));
typedef float  f32x4  __attribute__((ext_vector_type(4)));
typedef unsigned short ushort8v __attribute__((ext_vector_type(8)));

__device__ __forceinline__ unsigned short f2bf(float f) {
  union { float f; unsigned int u; } v; v.f = f;
  unsigned int r = v.u + 0x7fffu + ((v.u >> 16) & 1u);   // RNE
  return (unsigned short)(r >> 16);
}
__device__ __forceinline__ float bf2f(unsigned short h) {
  union { unsigned int u; float f; } v; v.u = ((unsigned int)h) << 16;
  return v.f;
}

__device__ __forceinline__ void gload_lds16(const void* g, void* l) {
  __builtin_amdgcn_global_load_lds((__attribute__((address_space(1))) void*)g,
                                   (__attribute__((address_space(3))) void*)l,
                                   16, 0, 0);
}

#define MFMA_ __builtin_amdgcn_mfma_f32_16x16x32_bf16
// lgkm0-then-barrier sync point, order pinned (rule #18)
#define SYNC_()  do { asm volatile("s_waitcnt lgkmcnt(0)" ::: "memory"); \
                      __builtin_amdgcn_sched_barrier(0); \
                      __builtin_amdgcn_s_barrier(); \
                      __builtin_amdgcn_sched_barrier(0); } while (0)

// ---------------------------------------------------------------------------
// D[m][n] = sum_k A[m][kofx+k] * B[n][k];  M=N=1024 per (batch, pair-slice).
// 256x256 tile, BK=64, 8 waves (2M x 4N, wave tile 128x64), LDS 2 x 64KB.
// OMODE 0: raw bf16 rows at col nofx; 1: scaled bf16 (Sigma_z);
// OMODE 3: r-gate fused sigma_g -> bf16 (SzP=SstH, zV=r, prevV=prev);
// OMODE 2: h-gate fused combine -> f32 (SzP=Sz, SstP=Sst, zV/prevV/hV).
// PAIR=1: panel index carries ps selecting {Bm,+0} / {Bm2,+1024 kofx,nofx}.
// ---------------------------------------------------------------------------
template<int OMODE, int PAIR>
__global__ __launch_bounds__(512)
void gemm8p(const unsigned short* __restrict__ A, int lda, long aStride, int koffA,
            const unsigned short* __restrict__ Bm, const unsigned short* __restrict__ Bm2,
            int ldb, long bStride, int K,
            void* __restrict__ Out, int ldo, long oStride, int noff,
            const float* __restrict__ act,
            const float* __restrict__ spU, const float* __restrict__ spW,
            const float* __restrict__ dU, const float* __restrict__ dW,
            const unsigned short* __restrict__ SzP, const float* __restrict__ SstP,
            const float* __restrict__ zV, const float* __restrict__ prevV,
            const float* __restrict__ hV)
{
  __shared__ __align__(16) char ldsb[131072];   // 2 x (A 32KB | B 32KB)
  const int id = blockIdx.x;
  const int xcd = id & 7, rest = id >> 3;
  const int mt = rest & 3, pp = rest >> 2;
  const int panel = xcd + (pp << 3);            // (nt, b, ps)
  const int nt = panel & 3;
  const int b  = (panel >> 2) & 15;
  const int ps = PAIR ? (panel >> 6) : 0;
  const unsigned short* Bsel = (PAIR && ps) ? Bm2 : Bm;
  const int kofx = koffA + (ps ? 1024 : 0);
  const int nofx = noff  + (ps ? 1024 : 0);
  const int mbase = mt << 8, nbase = nt << 8;
  const int tid = threadIdx.x, lane = tid & 63, w = tid >> 6;
  const int wm = w >> 2, wn = w & 3;            // 2M x 4N waves
  const int NT = K >> 6;                        // K-tiles of 64

  f32x4 acc[8][4];
  const f32x4 zero4 = {0.f, 0.f, 0.f, 0.f};
#pragma unroll
  for (int i = 0; i < 8; i++)
#pragma unroll
    for (int j = 0; j < 4; j++) acc[i][j] = zero4;

  // ---- staging addressing (pre-swizzled global src, linear LDS dest) ----
  const int l3 = lane >> 3, l7 = lane & 7;
  const int posg = l7 ^ l3;
  const int gr = (l3 << 1) + (posg >> 2);       // local row 0..15
  const int gc = (posg & 3) << 3;               // local col (elems)
  const int bi0 = w << 1, bi1 = bi0 + 1;
  const int rS0 = ((bi0 >> 1) << 4) + gr, cS0 = ((bi0 & 1) << 5) + gc;
  const int rS1 = ((bi1 >> 1) << 4) + gr, cS1 = ((bi1 & 1) << 5) + gc;
  const unsigned short* Ab = A + (size_t)b * aStride + (size_t)mbase * lda + kofx;
  const unsigned short* Bb = Bsel + (size_t)b * bStride + (size_t)nbase * ldb;
  const int d0 = w << 11, d1 = (w << 11) + 1024;   // wave-uniform byte offsets

  auto SA = [&](int tt, int h) {                // stage A half h of K-tile tt
    char* dst = ldsb + ((tt & 1) << 16) + (h << 14);
    const unsigned short* s = Ab + (size_t)(h << 7) * lda + ((size_t)tt << 6);
    gload_lds16(s + (size_t)rS0 * lda + cS0, dst + d0);
    gload_lds16(s + (size_t)rS1 * lda + cS1, dst + d1);
  };
  auto SB = [&](int tt, int h) {
    char* dst = ldsb + ((tt & 1) << 16) + 32768 + (h << 14);
    const unsigned short* s = Bb + (size_t)(h << 7) * ldb + ((size_t)tt << 6);
    gload_lds16(s + (size_t)rS0 * ldb + cS0, dst + d0);
    gload_lds16(s + (size_t)rS1 * ldb + cS1, dst + d1);
  };

  // ---- ds_read frag addressing (swizzled within 1KB blocks) ----
  const int lrow = lane & 15, c4 = lane >> 4;
  const int aoff = ((lrow >> 1) << 7) + (((((lrow & 1) << 2) | c4) ^ (lrow >> 1)) << 4);
  const int abase = wm << 14;                       // wave's A half
  const int bbase = 32768 + ((wn >> 1) << 14);      // wave's B half
  const int brg   = (wn & 1) << 2;
  auto LDA = [&](const char* pb, int mi, int ks) -> bf16x8 {
    return *(const bf16x8*)(pb + abase + (((mi << 1) + ks) << 10) + aoff);
  };
  auto LDB = [&](const char* pb, int ni, int ks) -> bf16x8 {
    return *(const bf16x8*)(pb + bbase + ((((brg + ni) << 1) + ks) << 10) + aoff);
  };

  // ---- prologue: tile0 full + tile1 B-halves; wait tile0 landed ----
  SA(0, 0); SA(0, 1); SB(0, 0); SB(0, 1);
  if (NT > 1) { SB(1, 0); SB(1, 1); }
  asm volatile("s_waitcnt vmcnt(4)" ::: "memory");
  __builtin_amdgcn_sched_barrier(0);
  __builtin_amdgcn_s_barrier();
  __builtin_amdgcn_sched_barrier(0);

  bf16x8 avA[4], avB[4], bvA[4], bvB[4];
#pragma unroll
  for (int i = 0; i < 4; i++) avB[i] = LDA(ldsb, i, 0);   // m0,k0 tile0
#pragma unroll
  for (int i = 0; i < 4; i++) bvB[i] = LDB(ldsb, i, 0);   // k0 tile0
  __builtin_amdgcn_sched_barrier(0);

  for (int kt = 0; kt < NT; ++kt) {
    const char* pb = ldsb + ((kt & 1) << 16);
    const char* pn = ldsb + (((kt + 1) & 1) << 16);
    // ---- P1: MFMA(m0,k0)[avB,bvB] | read av(m1,k0) | stage A0(t+1) ----
#pragma unroll
    for (int i = 0; i < 4; i++) avA[i] = LDA(pb, 4 + i, 0);
    if (kt + 1 < NT) SA(kt + 1, 0);
    __builtin_amdgcn_s_setprio(1);
#pragma unroll
    for (int ni = 0; ni < 4; ni++)
#pragma unroll
      for (int mi = 0; mi < 4; mi++)
        acc[mi][ni] = MFMA_(avB[mi], bvB[ni], acc[mi][ni], 0, 0, 0);
    __builtin_amdgcn_s_setprio(0);
    // ---- P2: MFMA(m1,k0)[avA,bvB] | read av(m0,k1)+bv(k1) | stage A1(t+1)
#pragma unroll
    for (int i = 0; i < 4; i++) avB[i] = LDA(pb, i, 1);
#pragma unroll
    for (int i = 0; i < 4; i++) bvA[i] = LDB(pb, i, 1);
    if (kt + 1 < NT) SA(kt + 1, 1);
    __builtin_amdgcn_s_setprio(1);
#pragma unroll
    for (int ni = 0; ni < 4; ni++)
#pragma unroll
      for (int mi = 0; mi < 4; mi++)
        acc[4 + mi][ni] = MFMA_(avA[mi], bvB[ni], acc[4 + mi][ni], 0, 0, 0);
    __builtin_amdgcn_s_setprio(0);
    // ---- BAR1: all waves' B(t) reads drained before P4's B(t+2) stage ----
    SYNC_();
    // ---- P3: MFMA(m0,k1)[avB,bvA] | read av(m1,k1) ----
#pragma unroll
    for (int i = 0; i < 4; i++) avA[i] = LDA(pb, 4 + i, 1);
    __builtin_amdgcn_s_setprio(1);
#pragma unroll
    for (int ni = 0; ni < 4; ni++)
#pragma unroll
      for (int mi = 0; mi < 4; mi++)
        acc[mi][ni] = MFMA_(avB[mi], bvA[ni], acc[mi][ni], 0, 0, 0);
    __builtin_amdgcn_s_setprio(0);
    // ---- P4: stage B(t+2); vmcnt; BAR2; read-ahead t+1; MFMA(m1,k1) ----
    if (kt + 2 < NT) {
      SB(kt + 2, 0); SB(kt + 2, 1);
      asm volatile("s_waitcnt vmcnt(4)" ::: "memory");
    } else {
      asm volatile("s_waitcnt vmcnt(0)" ::: "memory");
    }
    SYNC_();
    if (kt + 1 < NT) {
#pragma unroll
      for (int i = 0; i < 4; i++) avB[i] = LDA(pn, i, 0);
#pragma unroll
      for (int i = 0; i < 4; i++) bvB[i] = LDB(pn, i, 0);
    }
    __builtin_amdgcn_sched_barrier(0);
    __builtin_amdgcn_s_setprio(1);
#pragma unroll
    for (int ni = 0; ni < 4; ni++)
#pragma unroll
      for (int mi = 0; mi < 4; mi++)
        acc[4 + mi][ni] = MFMA_(avA[mi], bvA[ni], acc[4 + mi][ni], 0, 0, 0);
    __builtin_amdgcn_s_setprio(0);
  }

  // ======================== epilogues ========================
  __syncthreads();                           // ring dead; reuse as scratch
  unsigned short* scr = (unsigned short*)(ldsb + w * 16384);  // 16KB/wave
  const float* actb = act ? (act + b * N_) : nullptr;
  float dUb = 0.f, dWb = 0.f;
  if (OMODE != 0) { dUb = dU[b]; dWb = dW[b]; }

  // ---- pass 1: write (scaled) tile to wave-private scratch, bf16 ----
#pragma unroll
  for (int mi = 0; mi < 8; mi++) {
    const int rl0 = mi * 16 + ((lane >> 4) << 2);
#pragma unroll
    for (int ni = 0; ni < 4; ni++) {
      const int cl = ni * 16 + (lane & 15);
#pragma unroll
      for (int r = 0; r < 4; r++) {
        const int rl = rl0 + r;
        float val = acc[mi][ni][r];
        if (OMODE != 0) {
          const int u = mbase + wm * 128 + rl, v = nbase + wn * 64 + cl;
          if (u == v) val += dUb * spU[u] + dWb * spW[u];
          val *= actb[u] * actb[v];
        }
        scr[rl * 64 + ((((cl >> 3) ^ (rl & 7))) << 3) + (cl & 7)] = f2bf(val);
      }
    }
  }
  asm volatile("s_waitcnt lgkmcnt(0)" ::: "memory");
  __builtin_amdgcn_sched_barrier(0);

  // ---- pass 2: read back 8-wide, finish, store coalesced ----
#pragma unroll
  for (int pq = 0; pq < 16; pq++) {
    const int row = pq * 8 + (lane >> 3);
    const int slot = lane & 7;
    const int ch = slot ^ (row & 7);              // chunk held in this slot
    const int u = mbase + wm * 128 + row;
    const int v0 = nbase + wn * 64 + (ch << 3);
    ushort8v s8 = *(const ushort8v*)&scr[row * 64 + (slot << 3)];
    if (OMODE == 0 || OMODE == 1) {
      unsigned short* ob = (unsigned short*)Out + (size_t)b * oStride
                         + (size_t)u * ldo + nofx + v0;
      *(ushort8v*)ob = s8;
    } else if (OMODE == 3) {
      // sigma_g = stt*srv + p_u p_v srv + r_u r_v stt   (SzP=SstH, zV=r)
      const float pu = prevV[b * N_ + u];
      const float ru = zV[b * N_ + u];
      const ushort8v st8 = *(const ushort8v*)(SzP + (size_t)b * NN_ + (size_t)u * N_ + v0);
      const f32x4 pv0 = *(const f32x4*)(prevV + b * N_ + v0);
      const f32x4 pv1 = *(const f32x4*)(prevV + b * N_ + v0 + 4);
      const f32x4 rv0 = *(const f32x4*)(zV + b * N_ + v0);
      const f32x4 rv1 = *(const f32x4*)(zV + b * N_ + v0 + 4);
      ushort8v o8;
#pragma unroll
      for (int q = 0; q < 8; q++) {
        const float srv = bf2f((unsigned short)s8[q]);
        const float stt = bf2f((unsigned short)st8[q]);
        const float pv = (q < 4) ? pv0[q] : pv1[q - 4];
        const float rv = (q < 4) ? rv0[q] : rv1[q - 4];
        o8[q] = f2bf(stt * srv + pu * pv * srv + ru * rv * stt);
      }
      unsigned short* ob = (unsigned short*)Out + (size_t)b * oStride
                         + (size_t)u * ldo + v0;
      *(ushort8v*)ob = o8;
    } else {  // OMODE 2: full Sigma_out combine
      const float zu = zV[b * N_ + u];
      const float pu = prevV[b * N_ + u];
      const float hu = hV[b * N_ + u];
      const ushort8v sz8 = *(const ushort8v*)(SzP + (size_t)b * NN_ + (size_t)u * N_ + v0);
      const f32x4 st0 = *(const f32x4*)(SstP + (size_t)b * NN_ + (size_t)u * N_ + v0);
      const f32x4 st1 = *(const f32x4*)(SstP + (size_t)b * NN_ + (size_t)u * N_ + v0 + 4);
      const f32x4 zv0 = *(const f32x4*)(zV + b * N_ + v0);
      const f32x4 zv1 = *(const f32x4*)(zV + b * N_ + v0 + 4);
      const f32x4 pv0 = *(const f32x4*)(prevV + b * N_ + v0);
      const f32x4 pv1 = *(const f32x4*)(prevV + b * N_ + v0 + 4);
      const f32x4 hv0 = *(const f32x4*)(hV + b * N_ + v0);
      const f32x4 hv1 = *(const f32x4*)(hV + b * N_ + v0 + 4);
      f32x4 o0, o1;
#pragma unroll
      for (int q = 0; q < 8; q++) {
        const float shh = bf2f((unsigned short)s8[q]);
        const float szv = bf2f((unsigned short)sz8[q]);
        const float stt = (q < 4) ? st0[q] : st1[q - 4];
        const float zv  = (q < 4) ? zv0[q] : zv1[q - 4];
        const float pv  = (q < 4) ? pv0[q] : pv1[q - 4];
        const float hv  = (q < 4) ? hv0[q] : hv1[q - 4];
        float res = szv * stt + zu * zv * stt + pu * pv * szv
                  + szv * shh + (1.f - zu) * (1.f - zv) * shh + hu * hv * szv
                  - szv * (pu * hv) - szv * (hu * pv);
        if (!isfinite(res)) res = 0.f;
        if (u == v0 + q) res = fabsf(res);
        if (q < 4) o0[q] = res; else o1[q - 4] = res;
      }
      float* ob = (float*)Out + (size_t)b * oStride + (size_t)u * ldo + v0;
      *(f32x4*)ob = o0;
      *(f32x4*)(ob + 4) = o1;
    }
  }
}

// --------------------------- small kernels ---------------------------------

// both conversions in one launch: y-dim selects tensor
__global__ void conv_bf16_2(const float* __restrict__ in0, unsigned short* __restrict__ out0,
                            const float* __restrict__ in1, unsigned short* __restrict__ out1,
                            int n4)
{
  const float* in = blockIdx.y ? in1 : in0;
  unsigned short* out = blockIdx.y ? out1 : out0;
  int i = blockIdx.x * 256 + threadIdx.x;
  const int stride = gridDim.x * 256;
  for (; i < n4; i += stride) {
    const float4 v = ((const float4*)in)[i];
    ushort4 o;
    o.x = f2bf(v.x); o.y = f2bf(v.y); o.z = f2bf(v.z); o.w = f2bf(v.w);
    ((ushort4*)out)[i] = o;
  }
}

// AT_g[u][k] = (k<1024 ? U_g[k][u] : W_g[k-1024][u]) as bf16. grid(32,64,3).
__global__ void build_AT(const float* __restrict__ Uz, const float* __restrict__ Wz,
                         const float* __restrict__ Ur, const float* __restrict__ Wr,
                         const float* __restrict__ Uh, const float* __restrict__ Wh,
                         unsigned short* __restrict__ AT)
{
  __shared__ float tile[32][33];
  const int g = blockIdx.z;
  const float* U = g == 0 ? Uz : (g == 1 ? Ur : Uh);
  const float* W = g == 0 ? Wz : (g == 1 ? Wr : Wh);
  const int u0  = blockIdx.x * 32;
  const int k0g = blockIdx.y * 32;
  const float* src = (k0g >= 1024) ? W : U;
  const int kloc = k0g & 1023;
  const int tx = threadIdx.x & 31, ty = threadIdx.x >> 5;
  unsigned short* out = AT + (size_t)g * N_ * 2048;
#pragma unroll
  for (int i = 0; i < 32; i += 8) tile[ty + i][tx] = src[(size_t)(kloc + ty + i) * N_ + u0 + tx];
  __syncthreads();
#pragma unroll
  for (int i = 0; i < 32; i += 8)
    out[(size_t)(u0 + ty + i) * 2048 + k0g + tx] = f2bf(tile[tx][ty + i]);
}

__global__ void softplus6(const float* a0, const float* a1, const float* a2,
                          const float* a3, const float* a4, const float* a5,
                          float* __restrict__ sp)
{
  const float* src[6] = {a0, a1, a2, a3, a4, a5};
  const int g = blockIdx.x;
  const float* s = src[g];
  for (int i = threadIdx.x; i < N_; i += 256) {
    float x = s[i];
    sp[g * N_ + i] = (x > 20.f) ? x : log1pf(expf(x));
  }
}

__global__ void scalars1(const float* __restrict__ mu, const float* __restrict__ prev,
                         const float* __restrict__ sin_, const float* __restrict__ Sst,
                         float* __restrict__ dA, float* __restrict__ dBzr)
{
  __shared__ float red[256];
  const int b = blockIdx.x;
  float s1 = 0.f, s2 = 0.f;
  for (int i = threadIdx.x; i < N_; i += 256) {
    const float m = mu[b * N_ + i];
    s1 += m * m + sin_[(size_t)b * NN_ + (size_t)i * (N_ + 1)];
    const float p = prev[b * N_ + i];
    s2 += p * p + Sst[(size_t)b * NN_ + (size_t)i * (N_ + 1)];
  }
  red[threadIdx.x] = s1; __syncthreads();
  for (int s = 128; s > 0; s >>= 1) { if (threadIdx.x < s) red[threadIdx.x] += red[threadIdx.x + s]; __syncthreads(); }
  if (threadIdx.x == 0) dA[b] = red[0];
  __syncthreads();
  red[threadIdx.x] = s2; __syncthreads();
  for (int s = 128; s > 0; s >>= 1) { if (threadIdx.x < s) red[threadIdx.x] += red[threadIdx.x + s]; __syncthreads(); }
  if (threadIdx.x == 0) dBzr[b] = red[0];
}

// ---- gate pre-activations, split-K partials (deterministic, no atomics) ----
__global__ __launch_bounds__(256)
void gate_pre2(const float* __restrict__ x1, const float* __restrict__ x2,
               const float* __restrict__ U0, const float* __restrict__ W0,
               const float* __restrict__ U1, const float* __restrict__ W1,
               float* __restrict__ Ppart)
{
  const int g  = blockIdx.z;
  const int ks = blockIdx.y;
  const int out = blockIdx.x * 256 + threadIdx.x;
  const int b = out >> 10, col = out & 1023;
  const float* x = (ks < 4) ? x1 : x2;
  const float* Wm = (g == 0) ? ((ks < 4) ? U0 : W0) : ((ks < 4) ? U1 : W1);
  const int k0 = (ks & 3) * 256;
  const float* xb = x + b * N_ + k0;
  const float* wp = Wm + (size_t)k0 * N_ + col;
  float acc = 0.f;
#pragma unroll 8
  for (int k = 0; k < 256; k++)
    acc += xb[k] * wp[(size_t)k * N_];
  Ppart[(g * 8 + ks) * (B_ * N_) + out] = acc;
}

__global__ void gate_act2(const float* __restrict__ P,
                          float* __restrict__ z, float* __restrict__ gz,
                          float* __restrict__ r, float* __restrict__ gr)
{
  const int out = blockIdx.x * 256 + threadIdx.x;
  float a0 = 0.f, a1 = 0.f;
#pragma unroll
  for (int ks = 0; ks < 8; ks++) {
    a0 += P[ks * (B_ * N_) + out];
    a1 += P[(8 + ks) * (B_ * N_) + out];
  }
  const float s0 = 1.f / (1.f + expf(-a0));
  const float s1 = 1.f / (1.f + expf(-a1));
  z[out] = s0; gz[out] = s0 * (1.f - s0);
  r[out] = s1; gr[out] = s1 * (1.f - s1);
}

__global__ __launch_bounds__(256)
void gate_pre1(const float* __restrict__ x1, const float* __restrict__ x2,
               const float* __restrict__ U0, const float* __restrict__ W0,
               float* __restrict__ Ppart)
{
  const int ks = blockIdx.y;
  const int out = blockIdx.x * 256 + threadIdx.x;
  const int b = out >> 10, col = out & 1023;
  const float* x = (ks < 4) ? x1 : x2;
  const float* Wm = (ks < 4) ? U0 : W0;
  const int k0 = (ks & 3) * 256;
  const float* xb = x + b * N_ + k0;
  const float* wp = Wm + (size_t)k0 * N_ + col;
  float acc = 0.f;
#pragma unroll 8
  for (int k = 0; k < 256; k++)
    acc += xb[k] * wp[(size_t)k * N_];
  Ppart[ks * (B_ * N_) + out] = acc;
}

// h, gh, and mu_out = z*prev + (1-z)*h   (mu folded in)
__global__ void gate_act1(const float* __restrict__ P,
                          const float* __restrict__ z, const float* __restrict__ prev,
                          float* __restrict__ h, float* __restrict__ gh,
                          float* __restrict__ mu_out)
{
  const int out = blockIdx.x * 256 + threadIdx.x;
  float a0 = 0.f;
#pragma unroll
  for (int ks = 0; ks < 8; ks++) a0 += P[ks * (B_ * N_) + out];
  const float s = tanhf(a0);
  h[out] = s; gh[out] = 1.f - s * s;
  const float zz = z[out];
  mu_out[out] = zz * prev[out] + (1.f - zz) * s;
}

__global__ void sr_csr(const float* __restrict__ prev, const float* __restrict__ r,
                       float* __restrict__ sr, float* __restrict__ csr)
{
  __shared__ float red[256];
  const int b = blockIdx.x;
  float s = 0.f;
  for (int i = threadIdx.x; i < N_; i += 256) {
    const float v = prev[b * N_ + i] * r[b * N_ + i];
    sr[b * N_ + i] = v;
    s += v * v;
  }
  red[threadIdx.x] = s; __syncthreads();
  for (int k = 128; k > 0; k >>= 1) { if (threadIdx.x < k) red[threadIdx.x] += red[threadIdx.x + k]; __syncthreads(); }
  if (threadIdx.x == 0) csr[b] = red[0];
}

__global__ void scalars2(const unsigned short* __restrict__ Sg,
                         const float* __restrict__ csr, float* __restrict__ dBh)
{
  __shared__ float red[256];
  const int b = blockIdx.x;
  float s = 0.f;
  for (int i = threadIdx.x; i < N_; i += 256)
    s += bf2f(Sg[(size_t)b * NN_ + (size_t)i * (N_ + 1)]);
  red[threadIdx.x] = s; __syncthreads();
  for (int k = 128; k > 0; k >>= 1) { if (threadIdx.x < k) red[threadIdx.x] += red[threadIdx.x + k]; __syncthreads(); }
  if (threadIdx.x == 0) dBh[b] = red[0] + csr[b];
}

// ---------------------------------------------------------------------------

extern "C" void kernel_launch(void* const* d_in, const int* in_sizes, int n_in,
                              void* d_out, int out_size, void* d_ws, size_t ws_size,
                              hipStream_t stream)
{
  const float* mu   = (const float*)d_in[0];
  const float* sin_ = (const float*)d_in[1];
  const float* prev = (const float*)d_in[2];
  const float* Sst  = (const float*)d_in[3];
  const float* Uz = (const float*)d_in[4];  const float* uzs = (const float*)d_in[5];
  const float* Wz = (const float*)d_in[6];  const float* wzs = (const float*)d_in[7];
  const float* Ur = (const float*)d_in[8];  const float* urs = (const float*)d_in[9];
  const float* Wr = (const float*)d_in[10]; const float* wrs = (const float*)d_in[11];
  const float* Uh = (const float*)d_in[12]; const float* uhs = (const float*)d_in[13];
  const float* Wh = (const float*)d_in[14]; const float* whs = (const float*)d_in[15];

  char* ws = (char*)d_ws;
  size_t off = 0;
  auto take = [&](size_t bytes) -> char* {
    char* p = ws + off;
    off = (off + bytes + 255) & ~(size_t)255;
    return p;
  };
  unsigned short* Tcm = (unsigned short*)take((size_t)B_ * 2048 * 1024 * 2); // 64 MB
  unsigned short* Sz  = (unsigned short*)take((size_t)B_ * NN_ * 2);        // 32 MB
  unsigned short* Sg  = (unsigned short*)take((size_t)B_ * NN_ * 2);        // 32 MB
  unsigned short* AT  = (unsigned short*)take((size_t)3 * N_ * 2048 * 2);   // 12 MB
  float* Ppart = (float*)take((size_t)16 * B_ * N_ * 4);                    // 1 MB
  float* sp   = (float*)take(6 * N_ * 4);
  float* z    = (float*)take(B_ * N_ * 4);
  float* gz   = (float*)take(B_ * N_ * 4);
  float* rr   = (float*)take(B_ * N_ * 4);
  float* gr   = (float*)take(B_ * N_ * 4);
  float* h    = (float*)take(B_ * N_ * 4);
  float* gh   = (float*)take(B_ * N_ * 4);
  float* sr   = (float*)take(B_ * N_ * 4);
  float* dA   = (float*)take(64);
  float* dBzr = (float*)take(64);
  float* dBh  = (float*)take(64);
  float* csr  = (float*)take(64);
  if (off > ws_size) return;  // workspace too small (needs ~142 MB)

  float* mu_out = (float*)d_out;
  float* SigOut = (float*)d_out + (size_t)B_ * N_;
  // bf16 copies of the two big f32 inputs live in SigOut's dead region
  // (fully overwritten by the fused h-gate stage-2 at the end).
  unsigned short* SinH = (unsigned short*)SigOut;                 // 32 MB
  unsigned short* SstH = (unsigned short*)SigOut + (size_t)B_ * NN_; // 32 MB

  const unsigned short* ATz = AT;
  const unsigned short* ATr = AT + (size_t)N_ * 2048;
  const unsigned short* ATh = AT + (size_t)2 * N_ * 2048;

  // ---- prep ----
  conv_bf16_2<<<dim3(2048, 2), 256, 0, stream>>>(sin_, SinH, Sst, SstH, B_ * NN_ / 4);
  softplus6<<<6, 256, 0, stream>>>(uzs, wzs, urs, wrs, uhs, whs, sp);
  scalars1<<<16, 256, 0, stream>>>(mu, prev, sin_, Sst, dA, dBzr);
  build_AT<<<dim3(32, 64, 3), 256, 0, stream>>>(Uz, Wz, Ur, Wr, Uh, Wh, AT);
  gate_pre2<<<dim3(64, 8, 2), 256, 0, stream>>>(mu, prev, Uz, Wz, Ur, Wr, Ppart);
  gate_act2<<<64, 256, 0, stream>>>(Ppart, z, gz, rr, gr);
  sr_csr<<<16, 256, 0, stream>>>(prev, rr, sr, csr);
  gate_pre1<<<dim3(64, 8), 256, 0, stream>>>(mu, sr, Uh, Wh, Ppart);
  gate_act1<<<64, 256, 0, stream>>>(Ppart, z, prev, h, gh, mu_out);

  const long tS = (long)2048 * 1024;

  // ---- z gate ----
  gemm8p<0, 1><<<512, 512, 0, stream>>>(ATz, 2048, 0, 0, SinH, SstH, 1024, (long)NN_, 1024,
                                        Tcm, 2048, tS, 0, nullptr, nullptr, nullptr, nullptr, nullptr,
                                        nullptr, nullptr, nullptr, nullptr, nullptr);
  gemm8p<1, 0><<<256, 512, 0, stream>>>(ATz, 2048, 0, 0, Tcm, nullptr, 2048, tS, 2048,
                                        Sz, 1024, (long)NN_, 0, gz, sp + 0, sp + 1024, dA, dBzr,
                                        nullptr, nullptr, nullptr, nullptr, nullptr);
  // ---- r gate (stage-2 fused with sigma_g) ----
  gemm8p<0, 1><<<512, 512, 0, stream>>>(ATr, 2048, 0, 0, SinH, SstH, 1024, (long)NN_, 1024,
                                        Tcm, 2048, tS, 0, nullptr, nullptr, nullptr, nullptr, nullptr,
                                        nullptr, nullptr, nullptr, nullptr, nullptr);
  gemm8p<3, 0><<<256, 512, 0, stream>>>(ATr, 2048, 0, 0, Tcm, nullptr, 2048, tS, 2048,
                                        Sg, 1024, (long)NN_, 0, gr, sp + 2048, sp + 3072, dA, dBzr,
                                        SstH, nullptr, rr, prev, nullptr);
  scalars2<<<16, 256, 0, stream>>>(Sg, csr, dBh);
  // ---- h gate (stage-2 fused with combine) ----
  gemm8p<0, 1><<<512, 512, 0, stream>>>(ATh, 2048, 0, 0, SinH, Sg, 1024, (long)NN_, 1024,
                                        Tcm, 2048, tS, 0, nullptr, nullptr, nullptr, nullptr, nullptr,
                                        nullptr, nullptr, nullptr, nullptr, nullptr);
  gemm8p<2, 0><<<256, 512, 0, stream>>>(ATh, 2048, 0, 0, Tcm, nullptr, 2048, tS, 2048,
                                        SigOut, 1024, (long)NN_, 0, gh, sp + 4096, sp + 5120, dA, dBh,
                                        Sz, Sst, z, prev, h);
}

// Round 15
// 513.051 us; speedup vs baseline: 1.0676x; 1.0008x over previous
//
#include <hip/hip_runtime.h>
#include <math.h>

// ---------------------------------------------------------------------------
// densityPropGRUCell: B=16, IN=U=1024.
// Round 15: ONE barrier per K-tile. B gets a 3-slot LDS ring (96KB) so the
// B(t+2) stage never aliases a live slot => BAR1 removed. A keeps 2 slots
// (64KB). Total LDS 160KB (gfx950 max). Sync point: BAR2 at P4
// (vmcnt(4) then lgkm0+barrier) — sole rendezvous per tile, hazard-verified:
//   A(t-1)/B(t-1) reads drained at BAR2(t-1) before SA(t+1)@P1(t)/SB(t+2)@P4(t)
//   overwrite those slots; all waves' staging landed (per-wave vmcnt before
//   barrier) before any wave's read-ahead of tile t+1.
// Epilogue fusions retained (OMODE 1 Sigma_z, 3 sigma_g, 2 combine).
// ---------------------------------------------------------------------------

#define B_  16
#define N_  1024
#define NN_ (1024*1024)

typedef __bf16 bf16x8 __attribute__((ext_vector_type(8)));
typedef float  f32x4  __attribute__((ext_vector_type(4)));
typedef unsigned short ushort8v __attribute__((ext_vector_type(8)));

__device__ __forceinline__ unsigned short f2bf(float f) {
  union { float f; unsigned int u; } v; v.f = f;
  unsigned int r = v.u + 0x7fffu + ((v.u >> 16) & 1u);   // RNE
  return (unsigned short)(r >> 16);
}
__device__ __forceinline__ float bf2f(unsigned short h) {
  union { unsigned int u; float f; } v; v.u = ((unsigned int)h) << 16;
  return v.f;
}

__device__ __forceinline__ void gload_lds16(const void* g, void* l) {
  __builtin_amdgcn_global_load_lds((__attribute__((address_space(1))) void*)g,
                                   (__attribute__((address_space(3))) void*)l,
                                   16, 0, 0);
}

#define MFMA_ __builtin_amdgcn_mfma_f32_16x16x32_bf16
// lgkm0-then-barrier sync point, order pinned (rule #18)
#define SYNC_()  do { asm volatile("s_waitcnt lgkmcnt(0)" ::: "memory"); \
                      __builtin_amdgcn_sched_barrier(0); \
                      __builtin_amdgcn_s_barrier(); \
                      __builtin_amdgcn_sched_barrier(0); } while (0)

// ---------------------------------------------------------------------------
// D[m][n] = sum_k A[m][kofx+k] * B[n][k];  M=N=1024 per (batch, pair-slice).
// 256x256 tile, BK=64, 8 waves (2M x 4N, wave tile 128x64).
// LDS: A 2x32KB at [0,64K); B 3x32KB at [64K,160K).
// OMODE 0: raw bf16 rows at col nofx; 1: scaled bf16 (Sigma_z);
// OMODE 3: r-gate fused sigma_g -> bf16 (SzP=SstH, zV=r, prevV=prev);
// OMODE 2: h-gate fused combine -> f32 (SzP=Sz, SstP=Sst, zV/prevV/hV).
// PAIR=1: panel index carries ps selecting {Bm,+0} / {Bm2,+1024 kofx,nofx}.
// ---------------------------------------------------------------------------
template<int OMODE, int PAIR>
__global__ __launch_bounds__(512)
void gemm8p(const unsigned short* __restrict__ A, int lda, long aStride, int koffA,
            const unsigned short* __restrict__ Bm, const unsigned short* __restrict__ Bm2,
            int ldb, long bStride, int K,
            void* __restrict__ Out, int ldo, long oStride, int noff,
            const float* __restrict__ act,
            const float* __restrict__ spU, const float* __restrict__ spW,
            const float* __restrict__ dU, const float* __restrict__ dW,
            const unsigned short* __restrict__ SzP, const float* __restrict__ SstP,
            const float* __restrict__ zV, const float* __restrict__ prevV,
            const float* __restrict__ hV)
{
  __shared__ __align__(16) char ldsb[163840];   // A 64KB | B 96KB
  const int id = blockIdx.x;
  const int xcd = id & 7, rest = id >> 3;
  const int mt = rest & 3, pp = rest >> 2;
  const int panel = xcd + (pp << 3);            // (nt, b, ps)
  const int nt = panel & 3;
  const int b  = (panel >> 2) & 15;
  const int ps = PAIR ? (panel >> 6) : 0;
  const unsigned short* Bsel = (PAIR && ps) ? Bm2 : Bm;
  const int kofx = koffA + (ps ? 1024 : 0);
  const int nofx = noff  + (ps ? 1024 : 0);
  const int mbase = mt << 8, nbase = nt << 8;
  const int tid = threadIdx.x, lane = tid & 63, w = tid >> 6;
  const int wm = w >> 2, wn = w & 3;            // 2M x 4N waves
  const int NT = K >> 6;                        // K-tiles of 64

  f32x4 acc[8][4];
  const f32x4 zero4 = {0.f, 0.f, 0.f, 0.f};
#pragma unroll
  for (int i = 0; i < 8; i++)
#pragma unroll
    for (int j = 0; j < 4; j++) acc[i][j] = zero4;

  // ---- staging addressing (pre-swizzled global src, linear LDS dest) ----
  const int l3 = lane >> 3, l7 = lane & 7;
  const int posg = l7 ^ l3;
  const int gr = (l3 << 1) + (posg >> 2);       // local row 0..15
  const int gc = (posg & 3) << 3;               // local col (elems)
  const int bi0 = w << 1, bi1 = bi0 + 1;
  const int rS0 = ((bi0 >> 1) << 4) + gr, cS0 = ((bi0 & 1) << 5) + gc;
  const int rS1 = ((bi1 >> 1) << 4) + gr, cS1 = ((bi1 & 1) << 5) + gc;
  const unsigned short* Ab = A + (size_t)b * aStride + (size_t)mbase * lda + kofx;
  const unsigned short* Bb = Bsel + (size_t)b * bStride + (size_t)nbase * ldb;
  const int d0 = w << 11, d1 = (w << 11) + 1024;   // wave-uniform byte offsets

  auto SA = [&](int tt, int h) {                // stage A half h of K-tile tt
    char* dst = ldsb + ((tt & 1) << 15) + (h << 14);
    const unsigned short* s = Ab + (size_t)(h << 7) * lda + ((size_t)tt << 6);
    gload_lds16(s + (size_t)rS0 * lda + cS0, dst + d0);
    gload_lds16(s + (size_t)rS1 * lda + cS1, dst + d1);
  };
  auto SB = [&](int tt, int h) {                // B slot = tt % 3
    char* dst = ldsb + 65536 + (tt % 3) * 32768 + (h << 14);
    const unsigned short* s = Bb + (size_t)(h << 7) * ldb + ((size_t)tt << 6);
    gload_lds16(s + (size_t)rS0 * ldb + cS0, dst + d0);
    gload_lds16(s + (size_t)rS1 * ldb + cS1, dst + d1);
  };

  // ---- ds_read frag addressing (swizzled within 1KB blocks) ----
  const int lrow = lane & 15, c4 = lane >> 4;
  const int aoff = ((lrow >> 1) << 7) + (((((lrow & 1) << 2) | c4) ^ (lrow >> 1)) << 4);
  const int abase = wm << 14;                       // wave's A half within slot
  const int bbase = ((wn >> 1) << 14);              // wave's B half within slot
  const int brg   = (wn & 1) << 2;
  auto LDA = [&](const char* pa, int mi, int ks) -> bf16x8 {
    return *(const bf16x8*)(pa + abase + (((mi << 1) + ks) << 10) + aoff);
  };
  auto LDB = [&](const char* pbv, int ni, int ks) -> bf16x8 {
    return *(const bf16x8*)(pbv + bbase + ((((brg + ni) << 1) + ks) << 10) + aoff);
  };

  // ---- prologue: tile0 full + tile1 B-halves; wait tile0 landed ----
  SA(0, 0); SA(0, 1); SB(0, 0); SB(0, 1);
  if (NT > 1) { SB(1, 0); SB(1, 1); }
  asm volatile("s_waitcnt vmcnt(4)" ::: "memory");
  __builtin_amdgcn_sched_barrier(0);
  __builtin_amdgcn_s_barrier();
  __builtin_amdgcn_sched_barrier(0);

  bf16x8 avA[4], avB[4], bvA[4], bvB[4];
#pragma unroll
  for (int i = 0; i < 4; i++) avB[i] = LDA(ldsb, i, 0);          // m0,k0 tile0
#pragma unroll
  for (int i = 0; i < 4; i++) bvB[i] = LDB(ldsb + 65536, i, 0);  // k0 tile0
  __builtin_amdgcn_sched_barrier(0);

  int bs = 0;                                   // B slot of tile kt (kt % 3)
  for (int kt = 0; kt < NT; ++kt) {
    const char* pa = ldsb + ((kt & 1) << 15);
    const char* pbv = ldsb + 65536 + bs * 32768;
    const int bsn = (bs == 2) ? 0 : bs + 1;
    const char* pan = ldsb + (((kt + 1) & 1) << 15);
    const char* pbn = ldsb + 65536 + bsn * 32768;
    // ---- P1: MFMA(m0,k0)[avB,bvB] | read av(m1,k0) | stage A0(t+1) ----
#pragma unroll
    for (int i = 0; i < 4; i++) avA[i] = LDA(pa, 4 + i, 0);
    if (kt + 1 < NT) SA(kt + 1, 0);
    __builtin_amdgcn_s_setprio(1);
#pragma unroll
    for (int ni = 0; ni < 4; ni++)
#pragma unroll
      for (int mi = 0; mi < 4; mi++)
        acc[mi][ni] = MFMA_(avB[mi], bvB[ni], acc[mi][ni], 0, 0, 0);
    __builtin_amdgcn_s_setprio(0);
    // ---- P2: MFMA(m1,k0)[avA,bvB] | read av(m0,k1)+bv(k1) | stage A1(t+1)
#pragma unroll
    for (int i = 0; i < 4; i++) avB[i] = LDA(pa, i, 1);
#pragma unroll
    for (int i = 0; i < 4; i++) bvA[i] = LDB(pbv, i, 1);
    if (kt + 1 < NT) SA(kt + 1, 1);
    __builtin_amdgcn_s_setprio(1);
#pragma unroll
    for (int ni = 0; ni < 4; ni++)
#pragma unroll
      for (int mi = 0; mi < 4; mi++)
        acc[4 + mi][ni] = MFMA_(avA[mi], bvB[ni], acc[4 + mi][ni], 0, 0, 0);
    __builtin_amdgcn_s_setprio(0);
    // ---- P3: MFMA(m0,k1)[avB,bvA] | read av(m1,k1) ----
#pragma unroll
    for (int i = 0; i < 4; i++) avA[i] = LDA(pa, 4 + i, 1);
    __builtin_amdgcn_s_setprio(1);
#pragma unroll
    for (int ni = 0; ni < 4; ni++)
#pragma unroll
      for (int mi = 0; mi < 4; mi++)
        acc[mi][ni] = MFMA_(avB[mi], bvA[ni], acc[mi][ni], 0, 0, 0);
    __builtin_amdgcn_s_setprio(0);
    // ---- P4: stage B(t+2); vmcnt; BAR; read-ahead t+1; MFMA(m1,k1) ----
    if (kt + 2 < NT) {
      SB(kt + 2, 0); SB(kt + 2, 1);
      asm volatile("s_waitcnt vmcnt(4)" ::: "memory");
    } else {
      asm volatile("s_waitcnt vmcnt(0)" ::: "memory");
    }
    SYNC_();
    if (kt + 1 < NT) {
#pragma unroll
      for (int i = 0; i < 4; i++) avB[i] = LDA(pan, i, 0);
#pragma unroll
      for (int i = 0; i < 4; i++) bvB[i] = LDB(pbn, i, 0);
    }
    __builtin_amdgcn_sched_barrier(0);
    __builtin_amdgcn_s_setprio(1);
#pragma unroll
    for (int ni = 0; ni < 4; ni++)
#pragma unroll
      for (int mi = 0; mi < 4; mi++)
        acc[4 + mi][ni] = MFMA_(avA[mi], bvA[ni], acc[4 + mi][ni], 0, 0, 0);
    __builtin_amdgcn_s_setprio(0);
    bs = bsn;
  }

  // ======================== epilogues ========================
  __syncthreads();                           // ring dead; reuse as scratch
  unsigned short* scr = (unsigned short*)(ldsb + w * 16384);  // 16KB/wave
  const float* actb = act ? (act + b * N_) : nullptr;
  float dUb = 0.f, dWb = 0.f;
  if (OMODE != 0) { dUb = dU[b]; dWb = dW[b]; }

  // ---- pass 1: write (scaled) tile to wave-private scratch, bf16 ----
#pragma unroll
  for (int mi = 0; mi < 8; mi++) {
    const int rl0 = mi * 16 + ((lane >> 4) << 2);
#pragma unroll
    for (int ni = 0; ni < 4; ni++) {
      const int cl = ni * 16 + (lane & 15);
#pragma unroll
      for (int r = 0; r < 4; r++) {
        const int rl = rl0 + r;
        float val = acc[mi][ni][r];
        if (OMODE != 0) {
          const int u = mbase + wm * 128 + rl, v = nbase + wn * 64 + cl;
          if (u == v) val += dUb * spU[u] + dWb * spW[u];
          val *= actb[u] * actb[v];
        }
        scr[rl * 64 + ((((cl >> 3) ^ (rl & 7))) << 3) + (cl & 7)] = f2bf(val);
      }
    }
  }
  asm volatile("s_waitcnt lgkmcnt(0)" ::: "memory");
  __builtin_amdgcn_sched_barrier(0);

  // ---- pass 2: read back 8-wide, finish, store coalesced ----
#pragma unroll
  for (int pq = 0; pq < 16; pq++) {
    const int row = pq * 8 + (lane >> 3);
    const int slot = lane & 7;
    const int ch = slot ^ (row & 7);              // chunk held in this slot
    const int u = mbase + wm * 128 + row;
    const int v0 = nbase + wn * 64 + (ch << 3);
    ushort8v s8 = *(const ushort8v*)&scr[row * 64 + (slot << 3)];
    if (OMODE == 0 || OMODE == 1) {
      unsigned short* ob = (unsigned short*)Out + (size_t)b * oStride
                         + (size_t)u * ldo + nofx + v0;
      *(ushort8v*)ob = s8;
    } else if (OMODE == 3) {
      // sigma_g = stt*srv + p_u p_v srv + r_u r_v stt   (SzP=SstH, zV=r)
      const float pu = prevV[b * N_ + u];
      const float ru = zV[b * N_ + u];
      const ushort8v st8 = *(const ushort8v*)(SzP + (size_t)b * NN_ + (size_t)u * N_ + v0);
      const f32x4 pv0 = *(const f32x4*)(prevV + b * N_ + v0);
      const f32x4 pv1 = *(const f32x4*)(prevV + b * N_ + v0 + 4);
      const f32x4 rv0 = *(const f32x4*)(zV + b * N_ + v0);
      const f32x4 rv1 = *(const f32x4*)(zV + b * N_ + v0 + 4);
      ushort8v o8;
#pragma unroll
      for (int q = 0; q < 8; q++) {
        const float srv = bf2f((unsigned short)s8[q]);
        const float stt = bf2f((unsigned short)st8[q]);
        const float pv = (q < 4) ? pv0[q] : pv1[q - 4];
        const float rv = (q < 4) ? rv0[q] : rv1[q - 4];
        o8[q] = f2bf(stt * srv + pu * pv * srv + ru * rv * stt);
      }
      unsigned short* ob = (unsigned short*)Out + (size_t)b * oStride
                         + (size_t)u * ldo + v0;
      *(ushort8v*)ob = o8;
    } else {  // OMODE 2: full Sigma_out combine
      const float zu = zV[b * N_ + u];
      const float pu = prevV[b * N_ + u];
      const float hu = hV[b * N_ + u];
      const ushort8v sz8 = *(const ushort8v*)(SzP + (size_t)b * NN_ + (size_t)u * N_ + v0);
      const f32x4 st0 = *(const f32x4*)(SstP + (size_t)b * NN_ + (size_t)u * N_ + v0);
      const f32x4 st1 = *(const f32x4*)(SstP + (size_t)b * NN_ + (size_t)u * N_ + v0 + 4);
      const f32x4 zv0 = *(const f32x4*)(zV + b * N_ + v0);
      const f32x4 zv1 = *(const f32x4*)(zV + b * N_ + v0 + 4);
      const f32x4 pv0 = *(const f32x4*)(prevV + b * N_ + v0);
      const f32x4 pv1 = *(const f32x4*)(prevV + b * N_ + v0 + 4);
      const f32x4 hv0 = *(const f32x4*)(hV + b * N_ + v0);
      const f32x4 hv1 = *(const f32x4*)(hV + b * N_ + v0 + 4);
      f32x4 o0, o1;
#pragma unroll
      for (int q = 0; q < 8; q++) {
        const float shh = bf2f((unsigned short)s8[q]);
        const float szv = bf2f((unsigned short)sz8[q]);
        const float stt = (q < 4) ? st0[q] : st1[q - 4];
        const float zv  = (q < 4) ? zv0[q] : zv1[q - 4];
        const float pv  = (q < 4) ? pv0[q] : pv1[q - 4];
        const float hv  = (q < 4) ? hv0[q] : hv1[q - 4];
        float res = szv * stt + zu * zv * stt + pu * pv * szv
                  + szv * shh + (1.f - zu) * (1.f - zv) * shh + hu * hv * szv
                  - szv * (pu * hv) - szv * (hu * pv);
        if (!isfinite(res)) res = 0.f;
        if (u == v0 + q) res = fabsf(res);
        if (q < 4) o0[q] = res; else o1[q - 4] = res;
      }
      float* ob = (float*)Out + (size_t)b * oStride + (size_t)u * ldo + v0;
      *(f32x4*)ob = o0;
      *(f32x4*)(ob + 4) = o1;
    }
  }
}

// --------------------------- small kernels ---------------------------------

// both conversions in one launch: y-dim selects tensor
__global__ void conv_bf16_2(const float* __restrict__ in0, unsigned short* __restrict__ out0,
                            const float* __restrict__ in1, unsigned short* __restrict__ out1,
                            int n4)
{
  const float* in = blockIdx.y ? in1 : in0;
  unsigned short* out = blockIdx.y ? out1 : out0;
  int i = blockIdx.x * 256 + threadIdx.x;
  const int stride = gridDim.x * 256;
  for (; i < n4; i += stride) {
    const float4 v = ((const float4*)in)[i];
    ushort4 o;
    o.x = f2bf(v.x); o.y = f2bf(v.y); o.z = f2bf(v.z); o.w = f2bf(v.w);
    ((ushort4*)out)[i] = o;
  }
}

// AT_g[u][k] = (k<1024 ? U_g[k][u] : W_g[k-1024][u]) as bf16. grid(32,64,3).
__global__ void build_AT(const float* __restrict__ Uz, const float* __restrict__ Wz,
                         const float* __restrict__ Ur, const float* __restrict__ Wr,
                         const float* __restrict__ Uh, const float* __restrict__ Wh,
                         unsigned short* __restrict__ AT)
{
  __shared__ float tile[32][33];
  const int g = blockIdx.z;
  const float* U = g == 0 ? Uz : (g == 1 ? Ur : Uh);
  const float* W = g == 0 ? Wz : (g == 1 ? Wr : Wh);
  const int u0  = blockIdx.x * 32;
  const int k0g = blockIdx.y * 32;
  const float* src = (k0g >= 1024) ? W : U;
  const int kloc = k0g & 1023;
  const int tx = threadIdx.x & 31, ty = threadIdx.x >> 5;
  unsigned short* out = AT + (size_t)g * N_ * 2048;
#pragma unroll
  for (int i = 0; i < 32; i += 8) tile[ty + i][tx] = src[(size_t)(kloc + ty + i) * N_ + u0 + tx];
  __syncthreads();
#pragma unroll
  for (int i = 0; i < 32; i += 8)
    out[(size_t)(u0 + ty + i) * 2048 + k0g + tx] = f2bf(tile[tx][ty + i]);
}

__global__ void softplus6(const float* a0, const float* a1, const float* a2,
                          const float* a3, const float* a4, const float* a5,
                          float* __restrict__ sp)
{
  const float* src[6] = {a0, a1, a2, a3, a4, a5};
  const int g = blockIdx.x;
  const float* s = src[g];
  for (int i = threadIdx.x; i < N_; i += 256) {
    float x = s[i];
    sp[g * N_ + i] = (x > 20.f) ? x : log1pf(expf(x));
  }
}

__global__ void scalars1(const float* __restrict__ mu, const float* __restrict__ prev,
                         const float* __restrict__ sin_, const float* __restrict__ Sst,
                         float* __restrict__ dA, float* __restrict__ dBzr)
{
  __shared__ float red[256];
  const int b = blockIdx.x;
  float s1 = 0.f, s2 = 0.f;
  for (int i = threadIdx.x; i < N_; i += 256) {
    const float m = mu[b * N_ + i];
    s1 += m * m + sin_[(size_t)b * NN_ + (size_t)i * (N_ + 1)];
    const float p = prev[b * N_ + i];
    s2 += p * p + Sst[(size_t)b * NN_ + (size_t)i * (N_ + 1)];
  }
  red[threadIdx.x] = s1; __syncthreads();
  for (int s = 128; s > 0; s >>= 1) { if (threadIdx.x < s) red[threadIdx.x] += red[threadIdx.x + s]; __syncthreads(); }
  if (threadIdx.x == 0) dA[b] = red[0];
  __syncthreads();
  red[threadIdx.x] = s2; __syncthreads();
  for (int s = 128; s > 0; s >>= 1) { if (threadIdx.x < s) red[threadIdx.x] += red[threadIdx.x + s]; __syncthreads(); }
  if (threadIdx.x == 0) dBzr[b] = red[0];
}

// ---- gate pre-activations, split-K partials (deterministic, no atomics) ----
__global__ __launch_bounds__(256)
void gate_pre2(const float* __restrict__ x1, const float* __restrict__ x2,
               const float* __restrict__ U0, const float* __restrict__ W0,
               const float* __restrict__ U1, const float* __restrict__ W1,
               float* __restrict__ Ppart)
{
  const int g  = blockIdx.z;
  const int ks = blockIdx.y;
  const int out = blockIdx.x * 256 + threadIdx.x;
  const int b = out >> 10, col = out & 1023;
  const float* x = (ks < 4) ? x1 : x2;
  const float* Wm = (g == 0) ? ((ks < 4) ? U0 : W0) : ((ks < 4) ? U1 : W1);
  const int k0 = (ks & 3) * 256;
  const float* xb = x + b * N_ + k0;
  const float* wp = Wm + (size_t)k0 * N_ + col;
  float acc = 0.f;
#pragma unroll 8
  for (int k = 0; k < 256; k++)
    acc += xb[k] * wp[(size_t)k * N_];
  Ppart[(g * 8 + ks) * (B_ * N_) + out] = acc;
}

__global__ void gate_act2(const float* __restrict__ P,
                          float* __restrict__ z, float* __restrict__ gz,
                          float* __restrict__ r, float* __restrict__ gr)
{
  const int out = blockIdx.x * 256 + threadIdx.x;
  float a0 = 0.f, a1 = 0.f;
#pragma unroll
  for (int ks = 0; ks < 8; ks++) {
    a0 += P[ks * (B_ * N_) + out];
    a1 += P[(8 + ks) * (B_ * N_) + out];
  }
  const float s0 = 1.f / (1.f + expf(-a0));
  const float s1 = 1.f / (1.f + expf(-a1));
  z[out] = s0; gz[out] = s0 * (1.f - s0);
  r[out] = s1; gr[out] = s1 * (1.f - s1);
}

__global__ __launch_bounds__(256)
void gate_pre1(const float* __restrict__ x1, const float* __restrict__ x2,
               const float* __restrict__ U0, const float* __restrict__ W0,
               float* __restrict__ Ppart)
{
  const int ks = blockIdx.y;
  const int out = blockIdx.x * 256 + threadIdx.x;
  const int b = out >> 10, col = out & 1023;
  const float* x = (ks < 4) ? x1 : x2;
  const float* Wm = (ks < 4) ? U0 : W0;
  const int k0 = (ks & 3) * 256;
  const float* xb = x + b * N_ + k0;
  const float* wp = Wm + (size_t)k0 * N_ + col;
  float acc = 0.f;
#pragma unroll 8
  for (int k = 0; k < 256; k++)
    acc += xb[k] * wp[(size_t)k * N_];
  Ppart[ks * (B_ * N_) + out] = acc;
}

// h, gh, and mu_out = z*prev + (1-z)*h   (mu folded in)
__global__ void gate_act1(const float* __restrict__ P,
                          const float* __restrict__ z, const float* __restrict__ prev,
                          float* __restrict__ h, float* __restrict__ gh,
                          float* __restrict__ mu_out)
{
  const int out = blockIdx.x * 256 + threadIdx.x;
  float a0 = 0.f;
#pragma unroll
  for (int ks = 0; ks < 8; ks++) a0 += P[ks * (B_ * N_) + out];
  const float s = tanhf(a0);
  h[out] = s; gh[out] = 1.f - s * s;
  const float zz = z[out];
  mu_out[out] = zz * prev[out] + (1.f - zz) * s;
}

__global__ void sr_csr(const float* __restrict__ prev, const float* __restrict__ r,
                       float* __restrict__ sr, float* __restrict__ csr)
{
  __shared__ float red[256];
  const int b = blockIdx.x;
  float s = 0.f;
  for (int i = threadIdx.x; i < N_; i += 256) {
    const float v = prev[b * N_ + i] * r[b * N_ + i];
    sr[b * N_ + i] = v;
    s += v * v;
  }
  red[threadIdx.x] = s; __syncthreads();
  for (int k = 128; k > 0; k >>= 1) { if (threadIdx.x < k) red[threadIdx.x] += red[threadIdx.x + k]; __syncthreads(); }
  if (threadIdx.x == 0) csr[b] = red[0];
}

__global__ void scalars2(const unsigned short* __restrict__ Sg,
                         const float* __restrict__ csr, float* __restrict__ dBh)
{
  __shared__ float red[256];
  const int b = blockIdx.x;
  float s = 0.f;
  for (int i = threadIdx.x; i < N_; i += 256)
    s += bf2f(Sg[(size_t)b * NN_ + (size_t)i * (N_ + 1)]);
  red[threadIdx.x] = s; __syncthreads();
  for (int k = 128; k > 0; k >>= 1) { if (threadIdx.x < k) red[threadIdx.x] += red[threadIdx.x + k]; __syncthreads(); }
  if (threadIdx.x == 0) dBh[b] = red[0] + csr[b];
}

// ---------------------------------------------------------------------------

extern "C" void kernel_launch(void* const* d_in, const int* in_sizes, int n_in,
                              void* d_out, int out_size, void* d_ws, size_t ws_size,
                              hipStream_t stream)
{
  const float* mu   = (const float*)d_in[0];
  const float* sin_ = (const float*)d_in[1];
  const float* prev = (const float*)d_in[2];
  const float* Sst  = (const float*)d_in[3];
  const float* Uz = (const float*)d_in[4];  const float* uzs = (const float*)d_in[5];
  const float* Wz = (const float*)d_in[6];  const float* wzs = (const float*)d_in[7];
  const float* Ur = (const float*)d_in[8];  const float* urs = (const float*)d_in[9];
  const float* Wr = (const float*)d_in[10]; const float* wrs = (const float*)d_in[11];
  const float* Uh = (const float*)d_in[12]; const float* uhs = (const float*)d_in[13];
  const float* Wh = (const float*)d_in[14]; const float* whs = (const float*)d_in[15];

  char* ws = (char*)d_ws;
  size_t off = 0;
  auto take = [&](size_t bytes) -> char* {
    char* p = ws + off;
    off = (off + bytes + 255) & ~(size_t)255;
    return p;
  };
  unsigned short* Tcm = (unsigned short*)take((size_t)B_ * 2048 * 1024 * 2); // 64 MB
  unsigned short* Sz  = (unsigned short*)take((size_t)B_ * NN_ * 2);        // 32 MB
  unsigned short* Sg  = (unsigned short*)take((size_t)B_ * NN_ * 2);        // 32 MB
  unsigned short* AT  = (unsigned short*)take((size_t)3 * N_ * 2048 * 2);   // 12 MB
  float* Ppart = (float*)take((size_t)16 * B_ * N_ * 4);                    // 1 MB
  float* sp   = (float*)take(6 * N_ * 4);
  float* z    = (float*)take(B_ * N_ * 4);
  float* gz   = (float*)take(B_ * N_ * 4);
  float* rr   = (float*)take(B_ * N_ * 4);
  float* gr   = (float*)take(B_ * N_ * 4);
  float* h    = (float*)take(B_ * N_ * 4);
  float* gh   = (float*)take(B_ * N_ * 4);
  float* sr   = (float*)take(B_ * N_ * 4);
  float* dA   = (float*)take(64);
  float* dBzr = (float*)take(64);
  float* dBh  = (float*)take(64);
  float* csr  = (float*)take(64);
  if (off > ws_size) return;  // workspace too small (needs ~142 MB)

  float* mu_out = (float*)d_out;
  float* SigOut = (float*)d_out + (size_t)B_ * N_;
  // bf16 copies of the two big f32 inputs live in SigOut's dead region
  // (fully overwritten by the fused h-gate stage-2 at the end).
  unsigned short* SinH = (unsigned short*)SigOut;                 // 32 MB
  unsigned short* SstH = (unsigned short*)SigOut + (size_t)B_ * NN_; // 32 MB

  const unsigned short* ATz = AT;
  const unsigned short* ATr = AT + (size_t)N_ * 2048;
  const unsigned short* ATh = AT + (size_t)2 * N_ * 2048;

  // ---- prep ----
  conv_bf16_2<<<dim3(2048, 2), 256, 0, stream>>>(sin_, SinH, Sst, SstH, B_ * NN_ / 4);
  softplus6<<<6, 256, 0, stream>>>(uzs, wzs, urs, wrs, uhs, whs, sp);
  scalars1<<<16, 256, 0, stream>>>(mu, prev, sin_, Sst, dA, dBzr);
  build_AT<<<dim3(32, 64, 3), 256, 0, stream>>>(Uz, Wz, Ur, Wr, Uh, Wh, AT);
  gate_pre2<<<dim3(64, 8, 2), 256, 0, stream>>>(mu, prev, Uz, Wz, Ur, Wr, Ppart);
  gate_act2<<<64, 256, 0, stream>>>(Ppart, z, gz, rr, gr);
  sr_csr<<<16, 256, 0, stream>>>(prev, rr, sr, csr);
  gate_pre1<<<dim3(64, 8), 256, 0, stream>>>(mu, sr, Uh, Wh, Ppart);
  gate_act1<<<64, 256, 0, stream>>>(Ppart, z, prev, h, gh, mu_out);

  const long tS = (long)2048 * 1024;

  // ---- z gate ----
  gemm8p<0, 1><<<512, 512, 0, stream>>>(ATz, 2048, 0, 0, SinH, SstH, 1024, (long)NN_, 1024,
                                        Tcm, 2048, tS, 0, nullptr, nullptr, nullptr, nullptr, nullptr,
                                        nullptr, nullptr, nullptr, nullptr, nullptr);
  gemm8p<1, 0><<<256, 512, 0, stream>>>(ATz, 2048, 0, 0, Tcm, nullptr, 2048, tS, 2048,
                                        Sz, 1024, (long)NN_, 0, gz, sp + 0, sp + 1024, dA, dBzr,
                                        nullptr, nullptr, nullptr, nullptr, nullptr);
  // ---- r gate (stage-2 fused with sigma_g) ----
  gemm8p<0, 1><<<512, 512, 0, stream>>>(ATr, 2048, 0, 0, SinH, SstH, 1024, (long)NN_, 1024,
                                        Tcm, 2048, tS, 0, nullptr, nullptr, nullptr, nullptr, nullptr,
                                        nullptr, nullptr, nullptr, nullptr, nullptr);
  gemm8p<3, 0><<<256, 512, 0, stream>>>(ATr, 2048, 0, 0, Tcm, nullptr, 2048, tS, 2048,
                                        Sg, 1024, (long)NN_, 0, gr, sp + 2048, sp + 3072, dA, dBzr,
                                        SstH, nullptr, rr, prev, nullptr);
  scalars2<<<16, 256, 0, stream>>>(Sg, csr, dBh);
  // ---- h gate (stage-2 fused with combine) ----
  gemm8p<0, 1><<<512, 512, 0, stream>>>(ATh, 2048, 0, 0, SinH, Sg, 1024, (long)NN_, 1024,
                                        Tcm, 2048, tS, 0, nullptr, nullptr, nullptr, nullptr, nullptr,
                                        nullptr, nullptr, nullptr, nullptr, nullptr);
  gemm8p<2, 0><<<256, 512, 0, stream>>>(ATh, 2048, 0, 0, Tcm, nullptr, 2048, tS, 2048,
                                        SigOut, 1024, (long)NN_, 0, gh, sp + 4096, sp + 5120, dA, dBh,
                                        Sz, Sst, z, prev, h);
}